// Round 7
// baseline (88.866 us; speedup 1.0000x reference)
//
#include <hip/hip_runtime.h>

// RankingLoss via bucket-ordering + per-chunk threshold tables (closed-form).
//   For t-sorted data, row i's qualifying set is a prefix. Its hinge sum is
//   sum_{p_j > theta} (p_j - theta), theta = p_i - m. Decompose the prefix into
//   complete 1024-chunks (answered from per-chunk p-bin tables + exact walk of
//   the single boundary p-bin) + <=1024 brute remainder + exact compare band.
//   K1 scatter_k(16 blocks): fused hist+scatter. Each block histograms ALL of
//      target (packed total|before counts, one LDS atomic), wave-scans, then
//      scatters its own 1024-elem range to exact sorted positions.
//   K2 chunk_k (16 blocks): per t-chunk: p-bin hist -> scan -> LDS rank scatter
//      (grouped by p-bin), per-bin double sums, suffix-summed.
//   K3 rank_k (512 blocks): paired groups (b, NG-1-b). Closed-form queries
//      (1 thread per row x chunk) + remainder pass + verified band.
//   K4 final_k (1 block): deterministic fixed-order double sum.
// NO device fences, no contended global atomics (R2 lesson).

constexpr float MARGIN = 0.1f;
constexpr int NBINS  = 256;   // t-bins (== T)
constexpr int PBINS  = 256;   // p-bins per chunk (== T)
constexpr int SB     = 16;    // scatter blocks; per-block range = n/SB = 1024
constexpr int CHUNK  = 1024;  // t-order chunk size
constexpr int NCHUNK = 16;    // n / CHUNK
constexpr int RT     = 16;    // rows per group
constexpr int T      = 256;   // threads per block

__device__ __forceinline__ int bin_of(float t) {
    int b = (int)(t * (float)NBINS);   // monotone; equal t -> equal bin
    b = b < 0 ? 0 : (b > NBINS - 1 ? NBINS - 1 : b);
    return b;
}
__device__ __forceinline__ int pbin_of(float p) {
    int b = (int)((p + 4.0f) * 32.0f); // monotone over the clamp; pred ~ N(0,1)
    b = b < 0 ? 0 : (b > PBINS - 1 ? PBINS - 1 : b);
    return b;
}

// K1: fused hist + scatter. lhp packs (total count | count before this block).
__global__ __launch_bounds__(T) void scatter_k(const float* __restrict__ pred,
                                               const float* __restrict__ target,
                                               float* __restrict__ ts,
                                               float* __restrict__ ps,
                                               int* __restrict__ Bg, int n) {
    __shared__ int lhp[NBINS];    // low16: total; high16: count in [0, base)
    __shared__ int sbase[NBINS];  // global bin start + prev-blocks count
    __shared__ int lcnt[NBINS];
    __shared__ int wsum[T / 64];

    const int tid = (int)threadIdx.x;
    const int k   = (int)blockIdx.x;
    lhp[tid] = 0; lcnt[tid] = 0;
    __syncthreads();

    const int per    = n / SB;        // 1024
    const int base   = k * per;
    const int basef4 = base >> 2;
    const int nf4    = n >> 2;        // 4096
    const float4* __restrict__ t4 = (const float4*)target;
    const float4* __restrict__ p4 = (const float4*)pred;

    for (int f = tid; f < nf4; f += T) {          // whole array: 16 float4/thread
        const float4 tv = t4[f];
        const int inc = (f < basef4) ? 0x10001 : 1;
        atomicAdd(&lhp[bin_of(tv.x)], inc);
        atomicAdd(&lhp[bin_of(tv.y)], inc);
        atomicAdd(&lhp[bin_of(tv.z)], inc);
        atomicAdd(&lhp[bin_of(tv.w)], inc);
    }
    __syncthreads();

    const int tot = lhp[tid] & 0xFFFF;
    const int prv = lhp[tid] >> 16;

    int incl = tot;                                // verified wave-scan
    #pragma unroll
    for (int off = 1; off < 64; off <<= 1) {
        int v = __shfl_up(incl, off, 64);
        if ((tid & 63) >= off) incl += v;
    }
    if ((tid & 63) == 63) wsum[tid >> 6] = incl;
    __syncthreads();
    int woff = 0;
    for (int w = 0; w < (tid >> 6); ++w) woff += wsum[w];
    const int bb = woff + incl - tot;
    sbase[tid] = bb + prv;
    if (k == 0) {                                  // block 0: prv==0, bb is global
        Bg[tid] = bb;
        if (tid == 0) Bg[NBINS] = n;
    }
    __syncthreads();

    const float4 tv = t4[basef4 + tid];            // own range: 1 float4/thread
    const float4 pvv = p4[basef4 + tid];
    { const int b = bin_of(tv.x); const int r = atomicAdd(&lcnt[b], 1);
      const int pos = sbase[b] + r; ts[pos] = tv.x; ps[pos] = pvv.x; }
    { const int b = bin_of(tv.y); const int r = atomicAdd(&lcnt[b], 1);
      const int pos = sbase[b] + r; ts[pos] = tv.y; ps[pos] = pvv.y; }
    { const int b = bin_of(tv.z); const int r = atomicAdd(&lcnt[b], 1);
      const int pos = sbase[b] + r; ts[pos] = tv.z; ps[pos] = pvv.z; }
    { const int b = bin_of(tv.w); const int r = atomicAdd(&lcnt[b], 1);
      const int pos = sbase[b] + r; ts[pos] = tv.w; ps[pos] = pvv.w; }
}

// K2: per-chunk p-bin tables: grouped values, bin starts, double suffix sums.
__global__ __launch_bounds__(T) void chunk_k(const float* __restrict__ ps,
                                             float* __restrict__ pv,
                                             int* __restrict__ binstart,
                                             double* __restrict__ sufsum) {
    __shared__ float spv[CHUNK];
    __shared__ int lh[PBINS];
    __shared__ int bb[PBINS + 1];
    __shared__ int lcnt[PBINS];
    __shared__ int wsum[T / 64];
    __shared__ double bsum[PBINS + 1];

    const int tid = (int)threadIdx.x;
    const int c   = (int)blockIdx.x;
    lh[tid] = 0; lcnt[tid] = 0;
    __syncthreads();

    float pl[4];
    #pragma unroll
    for (int qq = 0; qq < 4; ++qq) {
        pl[qq] = ps[c * CHUNK + tid + qq * T];
        atomicAdd(&lh[pbin_of(pl[qq])], 1);
    }
    __syncthreads();

    const int tot = lh[tid];
    int incl = tot;                                // verified wave-scan
    #pragma unroll
    for (int off = 1; off < 64; off <<= 1) {
        int v = __shfl_up(incl, off, 64);
        if ((tid & 63) >= off) incl += v;
    }
    if ((tid & 63) == 63) wsum[tid >> 6] = incl;
    __syncthreads();
    int woff = 0;
    for (int w = 0; w < (tid >> 6); ++w) woff += wsum[w];
    bb[tid] = woff + incl - tot;
    if (tid == 0) bb[PBINS] = CHUNK;
    __syncthreads();

    #pragma unroll
    for (int qq = 0; qq < 4; ++qq) {               // group by p-bin (LDS rank)
        const int b = pbin_of(pl[qq]);
        const int r = atomicAdd(&lcnt[b], 1);
        spv[bb[b] + r] = pl[qq];
    }
    __syncthreads();

    {                                              // per-bin double sum
        double s = 0.0;
        const int lo = bb[tid], hi = bb[tid + 1];
        for (int i = lo; i < hi; ++i) s += (double)spv[i];
        bsum[tid] = s;
        if (tid == 0) bsum[PBINS] = 0.0;
    }
    __syncthreads();
    for (int off = 1; off < PBINS; off <<= 1) {    // suffix sum over bins
        const double tr = (tid + off < PBINS) ? bsum[tid + off] : 0.0;
        __syncthreads();
        bsum[tid] += tr;
        __syncthreads();
    }

    #pragma unroll
    for (int qq = 0; qq < 4; ++qq) {
        const int i = tid + qq * T;
        pv[c * CHUNK + i] = spv[i];
    }
    binstart[c * (PBINS + 1) + tid] = bb[tid];
    sufsum[c * (PBINS + 1) + tid]  = bsum[tid];
    if (tid == 0) {
        binstart[c * (PBINS + 1) + PBINS] = CHUNK;
        sufsum[c * (PBINS + 1) + PBINS]   = 0.0;
    }
}

// K3: paired groups; closed-form chunks + remainder pass + verified band.
__global__ __launch_bounds__(T) void rank_k(const float* __restrict__ ts,
                                            const float* __restrict__ ps,
                                            const int* __restrict__ B,
                                            const float* __restrict__ pv,
                                            const int* __restrict__ binstart,
                                            const double* __restrict__ sufsum,
                                            float* __restrict__ partials, int n) {
    const int NG = n / RT;                      // 1024
    const int bid = (int)blockIdx.x;            // 512

    const float4* __restrict__ p4 = (const float4*)ps;
    const float4* __restrict__ t4 = (const float4*)ts;

    const int tid  = (int)threadIdx.x;
    const int lane = tid & 63;
    const int wv   = tid >> 6;
    __shared__ float ls[T / 64][RT];
    __shared__ unsigned int lc[T / 64][RT];
    __shared__ double dacc[T];

    float blockacc = 0.f;

    for (int gg = 0; gg < 2; ++gg) {
        const int g = (gg == 0) ? bid : (NG - 1 - bid);
        const int q = g * RT;

        float ti[RT], ci[RT];
        #pragma unroll
        for (int r = 0; r < RT; ++r) {
            ti[r] = ts[q + r];
            ci[r] = MARGIN - ps[q + r];
        }

        const int Blo = B[bin_of(ti[0])];
        const int Bhi = B[bin_of(ti[RT - 1]) + 1];
        const int M0 = Blo & ~3;
        int M1 = (Bhi + 3) & ~3;
        if (M1 > n) M1 = n;
        const int CH = M0 >> 10;                 // complete 1024-chunks
        const int f4 = M0 >> 2;

        // Closed-form: one (row, chunk) task per thread (<= 16*15 = 240 tasks).
        // NOTE: reload ci from memory (L1-hot) -- runtime-indexing ci[] would
        // spill the register array to scratch (rule #20).
        double cf = 0.0;
        {
            const int row = tid & (RT - 1);
            const int ch  = tid >> 4;
            if (ch < CH) {
                const float cirow = MARGIN - ps[q + row];
                const float th = -cirow;          // theta = p_i - m
                const int pb = pbin_of(th);
                const int* bsr = binstart + ch * (PBINS + 1);
                const int b0 = bsr[pb];
                const int b1 = bsr[pb + 1];
                cf = sufsum[ch * (PBINS + 1) + pb + 1]
                   + (double)cirow * (double)(CHUNK - b1);   // bins > pb
                const float* pvc = pv + ch * CHUNK;
                for (int i = b0; i < b1; ++i) {              // boundary bin exact
                    const float p = pvc[i];
                    if (p > th) cf += (double)p - (double)th;
                }
            }
        }
        dacc[tid] = cf;

        float sum[RT];
        #pragma unroll
        for (int r = 0; r < RT; ++r) sum[r] = 0.f;

        // Remainder of full region [CH*1024, M0): <=1024 elems, one guarded pass.
        {
            const int j = (CH << 8) + tid;
            if (j < f4) {
                const float4 pj = p4[j];
                #pragma unroll
                for (int r = 0; r < RT; ++r) {
                    sum[r] += fmaxf(0.f, ci[r] + pj.x);
                    sum[r] += fmaxf(0.f, ci[r] + pj.y);
                    sum[r] += fmaxf(0.f, ci[r] + pj.z);
                    sum[r] += fmaxf(0.f, ci[r] + pj.w);
                }
            }
        }

        // Boundary band [M0, M1): exact compares + ballot counts (verified).
        unsigned int cnt[RT];
        #pragma unroll
        for (int r = 0; r < RT; ++r) cnt[r] = 0u;

        const int m4lo = M0 >> 2, m4hi = M1 >> 2;
        const int iters = (m4hi - m4lo + T - 1) / T;
        for (int it = 0; it < iters; ++it) {
            const int j = m4lo + it * T + tid;
            const bool inb = j < m4hi;
            const int jc = inb ? j : m4lo;
            const float4 tj = t4[jc];
            const float4 pj = p4[jc];
            #pragma unroll
            for (int r = 0; r < RT; ++r) {
                { bool m = inb && (tj.x < ti[r]); float h = fmaxf(0.f, ci[r] + pj.x);
                  sum[r] += m ? h : 0.f; cnt[r] += (unsigned)__popcll(__ballot(m)); }
                { bool m = inb && (tj.y < ti[r]); float h = fmaxf(0.f, ci[r] + pj.y);
                  sum[r] += m ? h : 0.f; cnt[r] += (unsigned)__popcll(__ballot(m)); }
                { bool m = inb && (tj.z < ti[r]); float h = fmaxf(0.f, ci[r] + pj.z);
                  sum[r] += m ? h : 0.f; cnt[r] += (unsigned)__popcll(__ballot(m)); }
                { bool m = inb && (tj.w < ti[r]); float h = fmaxf(0.f, ci[r] + pj.w);
                  sum[r] += m ? h : 0.f; cnt[r] += (unsigned)__popcll(__ballot(m)); }
            }
        }

        // Block-level reduction (verified).
        #pragma unroll
        for (int r = 0; r < RT; ++r) {
            float sv = sum[r];
            #pragma unroll
            for (int off = 32; off > 0; off >>= 1) sv += __shfl_down(sv, off, 64);
            if (lane == 0) { ls[wv][r] = sv; lc[wv][r] = cnt[r]; }
        }
        __syncthreads();   // also covers dacc writes

        float val = 0.f;
        if (tid < RT) {
            float sv = 0.f;
            unsigned int c = (unsigned int)M0;   // full region counts every row
            #pragma unroll
            for (int w = 0; w < T / 64; ++w) { sv += ls[w][tid]; c += lc[w][tid]; }
            double rowclosed = 0.0;
            #pragma unroll
            for (int kk = 0; kk < T / RT; ++kk) rowclosed += dacc[tid + kk * RT];
            val = (c > 0u) ? (float)((rowclosed + (double)sv) / (double)c) : 0.f;
        }
        if (tid < 64) {
            #pragma unroll
            for (int off = 8; off > 0; off >>= 1) val += __shfl_down(val, off, 64);
        }
        if (tid == 0) blockacc += val;
        __syncthreads();                         // ls/lc/dacc reused next group
    }

    if (tid == 0) partials[bid] = blockacc;
}

// K4: deterministic fixed-order reduction of partials (512 floats).
__global__ __launch_bounds__(T) void final_k(const float* __restrict__ partials,
                                             float* __restrict__ out, int n, int nprt) {
    const int n4 = nprt >> 2;
    double s = 0.0;
    for (int i = (int)threadIdx.x; i < n4; i += T) {
        float4 v = ((const float4*)partials)[i];
        s += (double)v.x + (double)v.y + (double)v.z + (double)v.w;
    }
    #pragma unroll
    for (int off = 32; off > 0; off >>= 1) s += __shfl_down(s, off, 64);
    __shared__ double sd[T / 64];
    const int lane = (int)threadIdx.x & 63, wv = (int)threadIdx.x >> 6;
    if (lane == 0) sd[wv] = s;
    __syncthreads();
    if (threadIdx.x == 0) {
        double t = 0.0;
        #pragma unroll
        for (int w = 0; w < T / 64; ++w) t += sd[w];
        out[0] = (float)(t / (double)n);
    }
}

extern "C" void kernel_launch(void* const* d_in, const int* in_sizes, int n_in,
                              void* d_out, int out_size, void* d_ws, size_t ws_size,
                              hipStream_t stream) {
    const float* pred   = (const float*)d_in[0];
    const float* target = (const float*)d_in[1];
    const int n = in_sizes[0];                 // 16384
    const int NG = n / RT;                     // 1024
    const int NB = NG / 2;                     // 512 rank blocks

    char* w = (char*)d_ws;
    size_t o = 0;
    auto alloc = [&](size_t bytes) {
        void* p = w + o;
        o = (o + bytes + 255) & ~(size_t)255;
        return p;
    };
    float*  ts    = (float*)alloc((size_t)n * 4);
    float*  ps    = (float*)alloc((size_t)n * 4);
    int*    B     = (int*)alloc((size_t)(NBINS + 1) * 4);
    float*  pvb   = (float*)alloc((size_t)n * 4);
    int*    bst   = (int*)alloc((size_t)NCHUNK * (PBINS + 1) * 4);
    double* sfx   = (double*)alloc((size_t)NCHUNK * (PBINS + 1) * 8);
    float*  parts = (float*)alloc((size_t)NB * 4);

    scatter_k<<<SB, T, 0, stream>>>(pred, target, ts, ps, B, n);
    chunk_k<<<NCHUNK, T, 0, stream>>>(ps, pvb, bst, sfx);
    rank_k<<<NB, T, 0, stream>>>(ts, ps, B, pvb, bst, sfx, parts, n);
    final_k<<<1, T, 0, stream>>>(parts, (float*)d_out, n, NB);
}